// Round 1
// baseline (358.651 us; speedup 1.0000x reference)
//
#include <hip/hip_runtime.h>

#define EPS 1e-6f

// Segment stats for "max run of 1s": (len, prefix run, suffix run, max run).
struct RunStats { int len, pre, suf, mx; };

__device__ inline RunStats rcombine(const RunStats& a, const RunStats& b) {
    RunStats r;
    r.len = a.len + b.len;
    r.pre = (a.pre == a.len) ? (a.len + b.pre) : a.pre;
    r.suf = (b.suf == b.len) ? (b.len + a.suf) : b.suf;
    r.mx  = max(max(a.mx, b.mx), a.suf + b.pre);
    return r;
}

// One block (256 threads = 4 waves) per row of N=4096.
// Wave w covers elements [w*1024, (w+1)*1024): j=0..3 blocks of 256,
// lane covers 4 contiguous elements -> float4 loads, fully coalesced.
__global__ __launch_bounds__(256) void row_kernel(
        const float* __restrict__ yp, const float* __restrict__ yt,
        const float* __restrict__ dw,
        float* __restrict__ row_wbce, int* __restrict__ row_streak) {
    const int row  = blockIdx.x;
    const int lane = threadIdx.x & 63;
    const int wave = threadIdx.x >> 6;
    const long base = (long)row * 4096;

    float sum = 0.0f;
    RunStats wstat = {0, 0, 0, 0};   // identity for rcombine

    #pragma unroll
    for (int j = 0; j < 4; ++j) {
        const int e = wave * 1024 + j * 256 + lane * 4;
        const float4 p = *(const float4*)(yp + base + e);
        const float4 t = *(const float4*)(yt + base + e);
        const float4 w = *(const float4*)(dw + base + e);

        const float px[4] = {p.x, p.y, p.z, p.w};
        const float tx[4] = {t.x, t.y, t.z, t.w};
        const float wx[4] = {w.x, w.y, w.z, w.w};

        int bits = 0;
        #pragma unroll
        for (int c = 0; c < 4; ++c) {
            const float l1 = __logf(px[c] + EPS);
            const float l2 = __logf(1.0f - px[c] + EPS);
            const float bce = -(tx[c] * l1 + (1.0f - tx[c]) * l2);
            sum += wx[c] * bce;
            const bool pb = px[c] > 0.5f;       // y_bin
            const bool tb = tx[c] != 0.0f;      // y_true (exactly 0/1)
            bits |= (int)(pb == tb) << c;
        }

        // stats of this lane's 4 bits (element order: bit0 first)
        int run = 0, m = 0;
        #pragma unroll
        for (int c = 0; c < 4; ++c) {
            run = ((bits >> c) & 1) ? run + 1 : 0;
            m = max(m, run);
        }
        const int pre = (bits & 1) ? ((bits & 2) ? ((bits & 4) ? ((bits & 8) ? 4 : 3) : 2) : 1) : 0;

        // Ordered wave-64 tree reduce; len is uniform per step (alen), so pack
        // (pre, suf, mx) into one int -> 1 shuffle per step. Lane 0 result valid.
        int packed = pre | (run << 10) | (m << 20);
        int alen = 4;
        #pragma unroll
        for (int off = 1; off < 64; off <<= 1) {
            const int o = __shfl_down(packed, off);
            const int apre = packed & 1023, asuf = (packed >> 10) & 1023, amx = packed >> 20;
            const int bpre = o & 1023,      bsuf = (o >> 10) & 1023,      bmx = o >> 20;
            const int npre = (apre == alen) ? (alen + bpre) : apre;
            const int nsuf = (bsuf == alen) ? (alen + asuf) : bsuf;
            const int nmx  = max(max(amx, bmx), asuf + bpre);
            packed = npre | (nsuf << 10) | (nmx << 20);
            alen <<= 1;
        }
        RunStats g;
        g.len = 256;
        g.pre = packed & 1023;
        g.suf = (packed >> 10) & 1023;
        g.mx  = packed >> 20;
        wstat = rcombine(wstat, g);   // only lane 0's value is meaningful
    }

    // wave-sum of wbce partials (commutative, butterfly via shfl_down to lane 0)
    #pragma unroll
    for (int off = 32; off; off >>= 1) sum += __shfl_down(sum, off);

    __shared__ RunStats sstat[4];
    __shared__ float ssum[4];
    if (lane == 0) { sstat[wave] = wstat; ssum[wave] = sum; }
    __syncthreads();
    if (threadIdx.x == 0) {
        RunStats r = rcombine(rcombine(sstat[0], sstat[1]), rcombine(sstat[2], sstat[3]));
        row_wbce[row]   = ssum[0] + ssum[1] + ssum[2] + ssum[3];
        row_streak[row] = r.mx;
    }
}

__global__ __launch_bounds__(256) void finalize_kernel(
        const float* __restrict__ row_wbce, const int* __restrict__ row_streak,
        int rows, float* __restrict__ out) {
    double s = 0.0;
    long long st = 0;
    for (int i = threadIdx.x; i < rows; i += 256) {
        s  += (double)row_wbce[i];
        st += (long long)row_streak[i];
    }
    __shared__ double sd[256];
    __shared__ long long sl[256];
    sd[threadIdx.x] = s; sl[threadIdx.x] = st;
    __syncthreads();
    for (int o = 128; o; o >>= 1) {
        if (threadIdx.x < o) {
            sd[threadIdx.x] += sd[threadIdx.x + o];
            sl[threadIdx.x] += sl[threadIdx.x + o];
        }
        __syncthreads();
    }
    if (threadIdx.x == 0) {
        const double total = (double)rows * 4096.0;
        const double wbce = sd[0] / total;
        const double cwl  = 1.0 - (double)sl[0] / total;
        out[0] = (float)(0.5 * wbce + 0.5 * cwl);
    }
}

extern "C" void kernel_launch(void* const* d_in, const int* in_sizes, int n_in,
                              void* d_out, int out_size, void* d_ws, size_t ws_size,
                              hipStream_t stream) {
    const float* yp = (const float*)d_in[0];
    const float* yt = (const float*)d_in[1];
    const float* dw = (const float*)d_in[2];
    float* out = (float*)d_out;

    const int rows = in_sizes[0] / 4096;   // 8192
    float* row_wbce  = (float*)d_ws;
    int*   row_streak = (int*)((char*)d_ws + (size_t)rows * sizeof(float));

    row_kernel<<<rows, 256, 0, stream>>>(yp, yt, dw, row_wbce, row_streak);
    finalize_kernel<<<1, 256, 0, stream>>>(row_wbce, row_streak, rows, out);
}

// Round 2
// 349.443 us; speedup vs baseline: 1.0264x; 1.0264x over previous
//
#include <hip/hip_runtime.h>

#define EPS 1e-6f

struct RunStats { int len, pre, suf, mx; };

__device__ inline RunStats rcombine(const RunStats& a, const RunStats& b) {
    RunStats r;
    r.len = a.len + b.len;
    r.pre = (a.pre == a.len) ? (a.len + b.pre) : a.pre;
    r.suf = (b.suf == b.len) ? (b.len + a.suf) : b.suf;
    r.mx  = max(max(a.mx, b.mx), a.suf + b.pre);
    return r;
}

// One block (256 threads = 4 waves) per row of N=4096.
// Lane owns 16 CONTIGUOUS elements: [wave*1024 + lane*16, +16).
// Loads are 64B-strided per instruction but the 4 float4s per array cover the
// same 4KB region -> L1 serves the re-touched lines; one wave-reduce per wave.
__global__ __launch_bounds__(256) void row_kernel(
        const float* __restrict__ yp, const float* __restrict__ yt,
        const float* __restrict__ dw,
        float* __restrict__ row_wbce, int* __restrict__ row_streak) {
    const int row  = blockIdx.x;
    const int lane = threadIdx.x & 63;
    const int wave = threadIdx.x >> 6;
    const long base = (long)row * 4096 + wave * 1024 + lane * 16;

    float4 p[4], t[4], w[4];
    #pragma unroll
    for (int q = 0; q < 4; ++q) {
        p[q] = *(const float4*)(yp + base + q * 4);
        t[q] = *(const float4*)(yt + base + q * 4);
        w[q] = *(const float4*)(dw + base + q * 4);
    }

    float sum = 0.0f;          // accumulates w * log(selected) (negative)
    unsigned mask = 0;         // bit (q*4+c) = element correct
    #pragma unroll
    for (int q = 0; q < 4; ++q) {
        const float pp[4] = {p[q].x, p[q].y, p[q].z, p[q].w};
        const float tt[4] = {t[q].x, t[q].y, t[q].z, t[q].w};
        const float ww[4] = {w[q].x, w[q].y, w[q].z, w[q].w};
        #pragma unroll
        for (int c = 0; c < 4; ++c) {
            const bool tb = tt[c] != 0.0f;                       // y_true exactly 0/1
            const float v = (tb ? pp[c] : 1.0f - pp[c]) + EPS;   // arg of the single log
            sum = fmaf(ww[c], __logf(v), sum);
            const bool pb = pp[c] > 0.5f;
            mask |= (unsigned)(pb == tb) << (q * 4 + c);
        }
    }

    // per-lane run stats over the 16-bit mask (bit0 = first element)
    int pre = __builtin_ctz(~mask);           // trailing 1s; ==16 iff mask==0xffff
    int suf = __builtin_clz(~(mask << 16));   // leading 1s of the 16-bit field
    int mx = 0;
    { unsigned x = mask; while (x) { x &= (x << 1); ++mx; } }

    // wbce wave sum (commutative)
    #pragma unroll
    for (int off = 32; off; off >>= 1) sum += __shfl_down(sum, off);

    // ordered wave reduce of (pre,suf,mx): 5 packed 10-bit steps (fields <=512),
    // then a final unpacked step (fields may reach 1024).
    int packed = pre | (suf << 10) | (mx << 20);
    int alen = 16;
    #pragma unroll
    for (int off = 1; off < 32; off <<= 1) {
        const int o = __shfl_down(packed, off);
        const int apre = packed & 1023, asuf = (packed >> 10) & 1023, amx = packed >> 20;
        const int bpre = o & 1023,      bsuf = (o >> 10) & 1023,      bmx = o >> 20;
        const int npre = (apre == alen) ? (alen + bpre) : apre;
        const int nsuf = (bsuf == alen) ? (alen + asuf) : bsuf;
        const int nmx  = max(max(amx, bmx), asuf + bpre);
        packed = npre | (nsuf << 10) | (nmx << 20);
        alen <<= 1;
    }
    RunStats g;
    {   // final step: off = 32, alen = 512
        const int o = __shfl_down(packed, 32);
        const int apre = packed & 1023, asuf = (packed >> 10) & 1023, amx = packed >> 20;
        const int bpre = o & 1023,      bsuf = (o >> 10) & 1023,      bmx = o >> 20;
        g.len = 1024;
        g.pre = (apre == 512) ? (512 + bpre) : apre;
        g.suf = (bsuf == 512) ? (512 + asuf) : bsuf;
        g.mx  = max(max(amx, bmx), asuf + bpre);
    }

    __shared__ RunStats sstat[4];
    __shared__ float ssum[4];
    if (lane == 0) { sstat[wave] = g; ssum[wave] = sum; }
    __syncthreads();
    if (threadIdx.x == 0) {
        RunStats r = rcombine(rcombine(sstat[0], sstat[1]), rcombine(sstat[2], sstat[3]));
        row_wbce[row]   = -(ssum[0] + ssum[1] + ssum[2] + ssum[3]);
        row_streak[row] = r.mx;
    }
}

__global__ __launch_bounds__(1024) void finalize_kernel(
        const float* __restrict__ row_wbce, const int* __restrict__ row_streak,
        int rows, float* __restrict__ out) {
    double s = 0.0;
    long long st = 0;
    for (int i = threadIdx.x; i < rows; i += 1024) {
        s  += (double)row_wbce[i];
        st += (long long)row_streak[i];
    }
    __shared__ double sd[1024];
    __shared__ long long sl[1024];
    sd[threadIdx.x] = s; sl[threadIdx.x] = st;
    __syncthreads();
    for (int o = 512; o; o >>= 1) {
        if (threadIdx.x < o) {
            sd[threadIdx.x] += sd[threadIdx.x + o];
            sl[threadIdx.x] += sl[threadIdx.x + o];
        }
        __syncthreads();
    }
    if (threadIdx.x == 0) {
        const double total = (double)rows * 4096.0;
        const double wbce = sd[0] / total;
        const double cwl  = 1.0 - (double)sl[0] / total;
        out[0] = (float)(0.5 * wbce + 0.5 * cwl);
    }
}

extern "C" void kernel_launch(void* const* d_in, const int* in_sizes, int n_in,
                              void* d_out, int out_size, void* d_ws, size_t ws_size,
                              hipStream_t stream) {
    const float* yp = (const float*)d_in[0];
    const float* yt = (const float*)d_in[1];
    const float* dw = (const float*)d_in[2];
    float* out = (float*)d_out;

    const int rows = in_sizes[0] / 4096;   // 8192
    float* row_wbce   = (float*)d_ws;
    int*   row_streak = (int*)((char*)d_ws + (size_t)rows * sizeof(float));

    row_kernel<<<rows, 256, 0, stream>>>(yp, yt, dw, row_wbce, row_streak);
    finalize_kernel<<<1, 1024, 0, stream>>>(row_wbce, row_streak, rows, out);
}